// Round 6
// baseline (684.032 us; speedup 1.0000x reference)
//
#include <hip/hip_runtime.h>
#include <math.h>

#define B_ 64
#define K_ 4000
#define G_ 200
#define C_ 91
#define EPS_ 1e-9f
#define NW_ 16
typedef unsigned long long ull;

// ws layout (byte offsets); total use ~3.6 MB (same as R5)
#define WS_FLAG 0
#define WS_PART 256        // 64*4 f32
#define WS_CNT 1536        // 64 int
#define WS_MATCH 2048      // 64*200 u32 (p<<8|g)
#define WS_ROWUSED 53248   // 64*4000 bytes
#define WS_TOP 327680      // 64*2*200*16 ull = 3.28 MB

// list key: (iou_bits << 12) | (4095 - p)   — iou desc, then p asc; always > 0
// full key: (list << 8) | (255 - g)         — iou desc, p asc, g asc == argmax flat order
__device__ __forceinline__ float box_area(float4 a) {
#pragma clang fp contract(off)
  return fmaxf(a.z - a.x, 0.f) * fmaxf(a.w - a.y, 0.f);
}

// IoU; contract(off) => bit-identical across init and rescan
__device__ __forceinline__ float iou_ab(float4 a, float aA, float4 b, float aB) {
#pragma clang fp contract(off)
  float tlx = fmaxf(a.x, b.x), tly = fmaxf(a.y, b.y);
  float brx = fminf(a.z, b.z), bry = fminf(a.w, b.w);
  float w = fmaxf(brx - tlx, 0.f), h = fmaxf(bry - tly, 0.f);
  float inter = w * h;
  float uni = fmaxf(aA + aB - inter, EPS_);
  return inter / uni;
}

__device__ __forceinline__ float ciou_loss(float4 p, float4 g) {
  float tlx = fmaxf(p.x, g.x), tly = fmaxf(p.y, g.y);
  float brx = fminf(p.z, g.z), bry = fminf(p.w, g.w);
  float w = fmaxf(brx - tlx, 0.f), h = fmaxf(bry - tly, 0.f);
  float inter = w * h;
  float areaP = fmaxf(p.z - p.x, 0.f) * fmaxf(p.w - p.y, 0.f);
  float areaG = fmaxf(g.z - g.x, 0.f) * fmaxf(g.w - g.y, 0.f);
  float iou = inter / fmaxf(areaP + areaG - inter, EPS_);
  float px = (p.x + p.z) * 0.5f, py = (p.y + p.w) * 0.5f;
  float tx = (g.x + g.z) * 0.5f, ty = (g.y + g.w) * 0.5f;
  float rho2 = (px - tx) * (px - tx) + (py - ty) * (py - ty);
  float ex = fmaxf(p.z, g.z) - fminf(p.x, g.x);
  float ey = fmaxf(p.w, g.w) - fminf(p.y, g.y);
  float c2 = fmaxf(ex * ex + ey * ey, EPS_);
  float pw = fmaxf(p.z - p.x, EPS_), ph = fmaxf(p.w - p.y, EPS_);
  float tw = fmaxf(g.z - g.x, EPS_), th = fmaxf(g.w - g.y, EPS_);
  float dat = atanf(tw / th) - atanf(pw / ph);
  float v = (4.0f / (float)(M_PI * M_PI)) * dat * dat;
  float alpha = v / ((1.f - iou) + v + EPS_);
  return 1.f - (iou - rho2 / c2 - alpha * v);
}

// gt_mask layout detector (int8 bool vs 4-byte elems) — unchanged (passed R1-R5)
__global__ void kdetect(const unsigned char* m8, int* flag) {
  int b = threadIdx.x;
  int ok = 1;
  const unsigned char* r = m8 + b * G_;
  if (r[0] != 1) ok = 0;
  int seen0 = 0;
  for (int g = 0; g < G_; ++g) {
    unsigned char c = r[g];
    if (c > 1) { ok = 0; break; }
    if (c == 0) seen0 = 1;
    else if (seen0) { ok = 0; break; }
  }
  int all = __all(ok);
  if (b == 0) *flag = all ? 1 : 0;
}

__device__ __forceinline__ float block_sum(float v, float* s_red) {
  for (int off = 32; off > 0; off >>= 1) v += __shfl_xor(v, off);
  int lane = threadIdx.x & 63, wid = threadIdx.x >> 6;
  if (lane == 0) s_red[wid] = v;
  __syncthreads();
  float r = 0.f;
  if (wid == 0) {
    float t = (lane < NW_) ? s_red[lane] : 0.f;
    for (int off = 32; off > 0; off >>= 1) t += __shfl_xor(t, off);
    r = t;
  }
  __syncthreads();
  return r;  // valid at tid 0
}

__device__ __forceinline__ ull wave_maxkey(ull k) {
  for (int off = 32; off > 0; off >>= 1) {
    ull o = __shfl_xor(k, off);
    if (o > k) k = o;
  }
  return k;
}

// insert into register-resident sorted-desc top-16 (named regs: no scratch)
#define TOP16_INS(key)                                    \
  if ((key) > t15) {                                      \
    t15 = (key);                                          \
    ull tmp_;                                             \
    if (t15 > t14) { tmp_ = t14; t14 = t15; t15 = tmp_; } \
    if (t14 > t13) { tmp_ = t13; t13 = t14; t14 = tmp_; } \
    if (t13 > t12) { tmp_ = t12; t12 = t13; t13 = tmp_; } \
    if (t12 > t11) { tmp_ = t11; t11 = t12; t12 = tmp_; } \
    if (t11 > t10) { tmp_ = t10; t10 = t11; t11 = tmp_; } \
    if (t10 > t9)  { tmp_ = t9;  t9 = t10;  t10 = tmp_; } \
    if (t9 > t8)   { tmp_ = t8;  t8 = t9;   t9 = tmp_; }  \
    if (t8 > t7)   { tmp_ = t7;  t7 = t8;   t8 = tmp_; }  \
    if (t7 > t6)   { tmp_ = t6;  t6 = t7;   t7 = tmp_; }  \
    if (t6 > t5)   { tmp_ = t5;  t5 = t6;   t6 = tmp_; }  \
    if (t5 > t4)   { tmp_ = t4;  t4 = t5;   t5 = tmp_; }  \
    if (t4 > t3)   { tmp_ = t3;  t3 = t4;   t4 = tmp_; }  \
    if (t3 > t2)   { tmp_ = t2;  t2 = t3;   t3 = tmp_; }  \
    if (t2 > t1)   { tmp_ = t1;  t1 = t2;   t2 = tmp_; }  \
    if (t1 > t0)   { tmp_ = t0;  t0 = t1;   t1 = tmp_; }  \
  }

// merge two sorted-desc 16-lists into sorted-desc top-16; destroys x,y.
// constant indices only => stays in registers.
__device__ __forceinline__ void merge16(ull* __restrict__ d, ull* __restrict__ x,
                                        ull* __restrict__ y) {
#pragma unroll
  for (int o = 0; o < 16; ++o) {
    bool tx = x[0] >= y[0];
    d[o] = tx ? x[0] : y[0];
#pragma unroll
    for (int q = 0; q < 15; ++q) {
      ull nx = x[q + 1], ny = y[q + 1];
      x[q] = tx ? nx : x[q];
      y[q] = tx ? y[q] : ny;
    }
    x[15] = tx ? 0ull : x[15];
    y[15] = tx ? y[15] : 0ull;
  }
}

// ---- phase 1: per-(batch, half-row-slice) per-column top-16 lists -> ws ----
__global__ __launch_bounds__(1024) void kinit(const float* __restrict__ pred_boxes,
                                              const float* __restrict__ gt_boxes,
                                              const void* __restrict__ gt_mask,
                                              char* __restrict__ ws) {
  __shared__ float s_gx[G_], s_gy[G_], s_gz[G_], s_gw[G_], s_garea[G_];
  __shared__ unsigned char s_valid[G_];
  __shared__ ull s_mbuf[64][5][16];
  const int b = blockIdx.x >> 1, sl = blockIdx.x & 1;
  const int tid = threadIdx.x;
  const int msk8 = *(const int*)(ws + WS_FLAG);
  const float4* p4 = (const float4*)pred_boxes + (size_t)b * K_;
  const float4* g4 = (const float4*)gt_boxes + (size_t)b * G_;

  for (int g = tid; g < G_; g += 1024) {
    float4 gb = g4[g];
    s_gx[g] = gb.x; s_gy[g] = gb.y; s_gz[g] = gb.z; s_gw[g] = gb.w;
    s_garea[g] = box_area(gb);
    int v;
    if (msk8) v = ((const unsigned char*)gt_mask)[(size_t)b * G_ + g] != 0;
    else      v = ((const int*)gt_mask)[(size_t)b * G_ + g] != 0;
    s_valid[g] = (unsigned char)v;
  }
  __syncthreads();

  const int c = tid / 5, j = tid - 5 * c;  // 5 threads/col, 400 rows each
  const bool active = (tid < 1000) && s_valid[c];
  ull t0 = 0, t1 = 0, t2 = 0, t3 = 0, t4 = 0, t5 = 0, t6 = 0, t7 = 0;
  ull t8 = 0, t9 = 0, t10 = 0, t11 = 0, t12 = 0, t13 = 0, t14 = 0, t15 = 0;
  if (active) {
    float4 gb = make_float4(s_gx[c], s_gy[c], s_gz[c], s_gw[c]);
    float gA = s_garea[c];
    const int k0 = sl * 2000 + j * 400;
    for (int i = 0; i < 400; ++i) {
      int k = k0 + i;
      float4 pb = p4[k];
      float iou = iou_ab(pb, box_area(pb), gb, gA);
      ull e = ((ull)__float_as_uint(iou) << 12) | (ull)(4095 - k);
      TOP16_INS(e);
    }
  }
  ull* wtop = (ull*)(ws + WS_TOP) + (size_t)(b * 2 + sl) * G_ * 16;
  for (int r = 0; r < 4; ++r) {
    int rc = c - 64 * r;
    if (active && rc >= 0 && rc < 64) {
      s_mbuf[rc][j][0] = t0;   s_mbuf[rc][j][1] = t1;
      s_mbuf[rc][j][2] = t2;   s_mbuf[rc][j][3] = t3;
      s_mbuf[rc][j][4] = t4;   s_mbuf[rc][j][5] = t5;
      s_mbuf[rc][j][6] = t6;   s_mbuf[rc][j][7] = t7;
      s_mbuf[rc][j][8] = t8;   s_mbuf[rc][j][9] = t9;
      s_mbuf[rc][j][10] = t10; s_mbuf[rc][j][11] = t11;
      s_mbuf[rc][j][12] = t12; s_mbuf[rc][j][13] = t13;
      s_mbuf[rc][j][14] = t14; s_mbuf[rc][j][15] = t15;
    }
    __syncthreads();
    if (tid < 64) {
      int cc = 64 * r + tid;
      if (cc < G_) {
        if (s_valid[cc]) {
          int i0 = 0, i1 = 0, i2 = 0, i3 = 0, i4 = 0;
          for (int o = 0; o < 16; ++o) {
            ull v0 = (i0 < 16) ? s_mbuf[tid][0][i0] : 0ull;
            ull v1 = (i1 < 16) ? s_mbuf[tid][1][i1] : 0ull;
            ull v2 = (i2 < 16) ? s_mbuf[tid][2][i2] : 0ull;
            ull v3 = (i3 < 16) ? s_mbuf[tid][3][i3] : 0ull;
            ull v4 = (i4 < 16) ? s_mbuf[tid][4][i4] : 0ull;
            ull best = v0; int jb = 0;
            if (v1 > best) { best = v1; jb = 1; }
            if (v2 > best) { best = v2; jb = 2; }
            if (v3 > best) { best = v3; jb = 3; }
            if (v4 > best) { best = v4; jb = 4; }
            if (jb == 0) ++i0; else if (jb == 1) ++i1; else if (jb == 2) ++i2;
            else if (jb == 3) ++i3; else ++i4;
            wtop[cc * 16 + o] = best;
          }
        } else {
          for (int o = 0; o < 16; ++o) wtop[cc * 16 + o] = 0ull;
        }
      }
    }
    __syncthreads();
  }
}

// ---- phase 2: greedy matching, 1 wave/batch, zero barriers, double-pop ----
__global__ __launch_bounds__(64) void kmatch(const float* __restrict__ pred_boxes,
                                             const float* __restrict__ gt_boxes,
                                             char* __restrict__ ws) {
  __shared__ float s_gx[G_], s_gy[G_], s_gz[G_], s_gw[G_], s_garea[G_];
  __shared__ unsigned char s_rowused[4096];  // padded: speculative reads safe
  __shared__ ull s_toplist[G_][16];
  __shared__ int s_mp[G_];
  __shared__ unsigned short s_mg[G_];
  const int b = blockIdx.x;
  const int lane = threadIdx.x;
  const float4* p4 = (const float4*)pred_boxes + (size_t)b * K_;
  const float4* g4 = (const float4*)gt_boxes + (size_t)b * G_;

  for (int g = lane; g < G_; g += 64) {
    float4 gb = g4[g];
    s_gx[g] = gb.x; s_gy[g] = gb.y; s_gz[g] = gb.z; s_gw[g] = gb.w;
    s_garea[g] = box_area(gb);
  }
  for (int k = lane; k < 4096; k += 64) s_rowused[k] = 0;

  const ull* wtop = (const ull*)(ws + WS_TOP);
  ull key0 = 0, key1 = 0, key2 = 0, key3 = 0;
  int ptr0 = 16, ptr1 = 16, ptr2 = 16, ptr3 = 16;
  int cloc = 0;
#define SLOTLOAD(S)                                                         \
  { int col = S * 64 + lane;                                                \
    if (col < G_) {                                                         \
      ull La[16], Lb[16], Mf[16];                                           \
      _Pragma("unroll") for (int o = 0; o < 16; ++o)                        \
        La[o] = wtop[((size_t)(b * 2 + 0) * G_ + col) * 16 + o];            \
      _Pragma("unroll") for (int o = 0; o < 16; ++o)                        \
        Lb[o] = wtop[((size_t)(b * 2 + 1) * G_ + col) * 16 + o];            \
      merge16(Mf, La, Lb);                                                  \
      _Pragma("unroll") for (int o = 0; o < 16; ++o) s_toplist[col][o] = Mf[o]; \
      if (Mf[0] != 0ull) {                                                  \
        key##S = (Mf[0] << 8) | (ull)(255 - col); ptr##S = 1; ++cloc; } } }
  SLOTLOAD(0) SLOTLOAD(1) SLOTLOAD(2) SLOTLOAD(3)
#undef SLOTLOAD
  for (int off = 32; off > 0; off >>= 1) cloc += __shfl_xor(cloc, off);
  const int cnt = cloc;

  for (int step = 0; step < cnt;) {
    // lane-local top-2 of 4 slots
    ull a1 = key0, a2 = key1;
    if (key1 > key0) { a1 = key1; a2 = key0; }
    if (key2 > a1) { a2 = a1; a1 = key2; } else if (key2 > a2) a2 = key2;
    if (key3 > a1) { a2 = a1; a1 = key3; } else if (key3 > a2) a2 = key3;
    // wave top-2 reduce
    for (int off = 32; off > 0; off >>= 1) {
      ull b1 = __shfl_xor(a1, off), b2 = __shfl_xor(a2, off);
      if (b1 > a1) { a2 = (a1 > b2) ? a1 : b2; a1 = b1; }
      else { a2 = (b1 > a2) ? b1 : a2; }
    }
    const int p1 = 4095 - (int)((a1 >> 8) & 0xFFF);
    const int g1v = 255 - (int)(a1 & 0xFF);
    const int p2 = 4095 - (int)((a2 >> 8) & 0xFFF);
    const int g2v = 255 - (int)(a2 & 0xFF);
    // #1 and #2 are always different cols; if rows differ too, #2 is exactly
    // the next greedy pick (pop-1 demotions only touch cols whose row == p1).
    const bool do2 = (a2 != 0ull) && (p2 != p1) && (step + 1 < cnt);
    if (lane == 0) {
      s_mp[step] = p1; s_mg[step] = (unsigned short)g1v; s_rowused[p1] = 1;
      if (do2) { s_mp[step + 1] = p2; s_mg[step + 1] = (unsigned short)g2v; s_rowused[p2] = 1; }
    }
    __builtin_amdgcn_wave_barrier();
    const int gd2 = do2 ? g2v : -1;
    const int pd2 = do2 ? p2 : -1;
    int need = 0;
#define DEMOTE(S)                                                           \
    { int col = S * 64 + lane; ull kk = key##S;                             \
      if (kk != 0ull) {                                                     \
        if (col == g1v || col == gd2) { key##S = 0ull; }                    \
        else { int krow = 4095 - (int)((kk >> 8) & 0xFFF);                  \
          if (krow == p1 || krow == pd2) {                                  \
            ull nk = 0ull; int np = ptr##S;                                 \
            while (np < 16) {                                               \
              ull e0 = s_toplist[col][np];                                  \
              ull e1 = (np + 1 < 16) ? s_toplist[col][np + 1] : 0ull;       \
              int pr0 = 4095 - (int)((e0 >> 12) & 0xFFF);                   \
              int pr1 = 4095 - (int)((e1 >> 12) & 0xFFF);                   \
              unsigned char u0 = s_rowused[pr0];                            \
              unsigned char u1 = s_rowused[pr1];                            \
              if (e0 == 0ull) { np = 16; break; }                           \
              if (!u0) { nk = (e0 << 8) | (ull)(255 - col); np += 1; break; } \
              if (e1 == 0ull) { np = 16; break; }                           \
              if (!u1) { nk = (e1 << 8) | (ull)(255 - col); np += 2; break; } \
              np += 2;                                                      \
            }                                                               \
            ptr##S = np; key##S = nk;                                       \
            if (nk == 0ull) need |= (1 << S); } } } }
    DEMOTE(0) DEMOTE(1) DEMOTE(2) DEMOTE(3)
#undef DEMOTE
    // exact fallback: full rescan for exhausted columns (now rare at depth 16)
    while (__any(need)) {
      unsigned long long bal = __ballot(need != 0);
      int src = (int)__builtin_ctzll(bal);
      int myslot = need ? __builtin_ctz(need) : 0;
      int slot = __shfl(myslot, src);
      int col = slot * 64 + src;
      float4 gb = make_float4(s_gx[col], s_gy[col], s_gz[col], s_gw[col]);
      float gA = s_garea[col];
      ull r1 = 0ull, r2 = 0ull;
      for (int k = lane; k < K_; k += 64) {
        if (!s_rowused[k]) {
          float4 pb = p4[k];
          float iou = iou_ab(pb, box_area(pb), gb, gA);
          ull e = ((ull)__float_as_uint(iou) << 12) | (ull)(4095 - k);
          if (e > r1) { r2 = r1; r1 = e; }
          else if (e > r2) r2 = e;
        }
      }
      ull m1 = wave_maxkey(r1);
      ull cnd = (r1 == m1) ? r2 : r1;
      ull m2 = wave_maxkey(cnd);
      if (lane == src) {
        ull nk = (m1 << 8) | (ull)(255 - col);
        if (slot == 0) key0 = nk; else if (slot == 1) key1 = nk;
        else if (slot == 2) key2 = nk; else key3 = nk;
        int npv = m2 ? 15 : 16;
        if (m2) s_toplist[col][15] = m2;
        if (slot == 0) ptr0 = npv; else if (slot == 1) ptr1 = npv;
        else if (slot == 2) ptr2 = npv; else ptr3 = npv;
        need &= ~(1 << slot);
      }
    }
    step += do2 ? 2 : 1;
  }

  // dump results for kepi
  unsigned* mout = (unsigned*)(ws + WS_MATCH) + b * G_;
  for (int i = lane; i < cnt; i += 64)
    mout[i] = ((unsigned)s_mp[i] << 8) | (unsigned)s_mg[i];
  unsigned* ruo = (unsigned*)(ws + WS_ROWUSED + (size_t)b * K_);
  const unsigned* rus = (const unsigned*)s_rowused;
  for (int i = lane; i < K_ / 4; i += 64) ruo[i] = rus[i];
  if (lane == 0) ((int*)(ws + WS_CNT))[b] = cnt;
}

// ---- phase 3: CIoU + CE over matches, BCE objectness over all K ----
__global__ __launch_bounds__(1024) void kepi(const float* __restrict__ pred_boxes,
                                             const float* __restrict__ obj_logits,
                                             const float* __restrict__ cls_logits,
                                             const float* __restrict__ gt_boxes,
                                             const int* __restrict__ gt_labels,
                                             char* __restrict__ ws) {
  __shared__ float s_red[NW_];
  const int b = blockIdx.x;
  const int tid = threadIdx.x;
  const int cnt = ((const int*)(ws + WS_CNT))[b];
  const unsigned* mm = (const unsigned*)(ws + WS_MATCH) + b * G_;
  const unsigned char* ru = (const unsigned char*)(ws + WS_ROWUSED) + (size_t)b * K_;
  const float4* p4 = (const float4*)pred_boxes + (size_t)b * K_;
  const float4* g4 = (const float4*)gt_boxes + (size_t)b * G_;

  float lbox = 0.f, lcls = 0.f;
  for (int i = tid; i < cnt; i += 1024) {
    unsigned e = mm[i];
    int p = (int)(e >> 8), g = (int)(e & 0xFF);
    float4 pb = p4[p];
    float4 gb = g4[g];
    lbox += ciou_loss(pb, gb);
    int label = gt_labels[(size_t)b * G_ + g];
    const float* lg = cls_logits + ((size_t)b * K_ + p) * C_;
    float m = -1e30f;
    for (int cc = 0; cc < C_; ++cc) m = fmaxf(m, lg[cc]);
    float s = 0.f;
    for (int cc = 0; cc < C_; ++cc) s += expf(lg[cc] - m);
    lcls += (m + logf(s)) - lg[label];
  }
  float obj = 0.f;
  const float* ol = obj_logits + (size_t)b * K_;
  for (int k = tid; k < K_; k += 1024) {
    float x = ol[k];
    float sp = fmaxf(x, 0.f) + log1pf(expf(-fabsf(x)));  // softplus(x)
    if (ru[k]) sp -= x;                                  // - t*x
    obj += sp;
  }
  lbox = block_sum(lbox, s_red);
  lcls = block_sum(lcls, s_red);
  obj = block_sum(obj, s_red);
  if (tid == 0) {
    float* partials = (float*)(ws + WS_PART);
    float n = (float)cnt;
    float denom = fmaxf(n, 1.f);
    partials[b * 4 + 0] = lbox / denom;
    partials[b * 4 + 1] = lcls / denom;
    partials[b * 4 + 2] = obj;
    partials[b * 4 + 3] = (n > 0.f) ? 1.f : 0.f;
  }
}

__global__ void kfinal(const char* __restrict__ ws, float* __restrict__ out) {
  int b = threadIdx.x;  // 64 threads, one wave
  const float* partials = (const float*)(ws + WS_PART);
  float lb = partials[b * 4 + 0], lc = partials[b * 4 + 1];
  float ob = partials[b * 4 + 2], hf = partials[b * 4 + 3];
  float sb = lb * hf, sc = lc * hf, sh = hf, so = ob;
  for (int off = 32; off > 0; off >>= 1) {
    sb += __shfl_xor(sb, off);
    sc += __shfl_xor(sc, off);
    sh += __shfl_xor(sh, off);
    so += __shfl_xor(so, off);
  }
  if (b == 0) {
    float nb = fmaxf(sh, 1.f);
    float box = sb / nb, cls = sc / nb;
    float obj = so / (float)(B_ * K_);
    out[0] = 5.f * box + cls + obj;
    out[1] = box;
    out[2] = cls;
    out[3] = obj;
  }
}

extern "C" void kernel_launch(void* const* d_in, const int* in_sizes, int n_in,
                              void* d_out, int out_size, void* d_ws, size_t ws_size,
                              hipStream_t stream) {
  const float* pred_boxes = (const float*)d_in[0];
  const float* obj_logits = (const float*)d_in[1];
  const float* cls_logits = (const float*)d_in[2];
  const float* gt_boxes = (const float*)d_in[3];
  const int* gt_labels = (const int*)d_in[4];
  const void* gt_mask = d_in[5];
  float* out = (float*)d_out;
  char* ws = (char*)d_ws;

  hipLaunchKernelGGL(kdetect, dim3(1), dim3(64), 0, stream,
                     (const unsigned char*)gt_mask, (int*)(ws + WS_FLAG));
  hipLaunchKernelGGL(kinit, dim3(B_ * 2), dim3(1024), 0, stream,
                     pred_boxes, gt_boxes, gt_mask, ws);
  hipLaunchKernelGGL(kmatch, dim3(B_), dim3(64), 0, stream,
                     pred_boxes, gt_boxes, ws);
  hipLaunchKernelGGL(kepi, dim3(B_), dim3(1024), 0, stream,
                     pred_boxes, obj_logits, cls_logits, gt_boxes, gt_labels, ws);
  hipLaunchKernelGGL(kfinal, dim3(1), dim3(64), 0, stream, ws, out);
}

// Round 7
// 377.242 us; speedup vs baseline: 1.8132x; 1.8132x over previous
//
#include <hip/hip_runtime.h>
#include <math.h>

#define B_ 64
#define K_ 4000
#define G_ 200
#define C_ 91
#define EPS_ 1e-9f
#define NW_ 16
typedef unsigned long long ull;

// ws layout (byte offsets); total use ~2.0 MB
#define WS_FLAG 0
#define WS_PART 256        // 64*4 f32
#define WS_CNT 1536        // 64 int
#define WS_MATCH 2048      // 64*200 u32 (p<<8|g)
#define WS_ROWUSED 53248   // 64*4000 bytes
#define WS_TOP 327680      // 64*200*16 ull = 1.64 MB (final exact top-16 lists)

// list key: (iou_bits << 12) | (4095 - p)   — iou desc, then p asc; always > 0
// full key: (list << 8) | (255 - g)         — iou desc, p asc, g asc == argmax flat order
__device__ __forceinline__ float box_area(float4 a) {
#pragma clang fp contract(off)
  return fmaxf(a.z - a.x, 0.f) * fmaxf(a.w - a.y, 0.f);
}

// IoU; contract(off) => bit-identical across init and rescan
__device__ __forceinline__ float iou_ab(float4 a, float aA, float4 b, float aB) {
#pragma clang fp contract(off)
  float tlx = fmaxf(a.x, b.x), tly = fmaxf(a.y, b.y);
  float brx = fminf(a.z, b.z), bry = fminf(a.w, b.w);
  float w = fmaxf(brx - tlx, 0.f), h = fmaxf(bry - tly, 0.f);
  float inter = w * h;
  float uni = fmaxf(aA + aB - inter, EPS_);
  return inter / uni;
}

__device__ __forceinline__ float ciou_loss(float4 p, float4 g) {
  float tlx = fmaxf(p.x, g.x), tly = fmaxf(p.y, g.y);
  float brx = fminf(p.z, g.z), bry = fminf(p.w, g.w);
  float w = fmaxf(brx - tlx, 0.f), h = fmaxf(bry - tly, 0.f);
  float inter = w * h;
  float areaP = fmaxf(p.z - p.x, 0.f) * fmaxf(p.w - p.y, 0.f);
  float areaG = fmaxf(g.z - g.x, 0.f) * fmaxf(g.w - g.y, 0.f);
  float iou = inter / fmaxf(areaP + areaG - inter, EPS_);
  float px = (p.x + p.z) * 0.5f, py = (p.y + p.w) * 0.5f;
  float tx = (g.x + g.z) * 0.5f, ty = (g.y + g.w) * 0.5f;
  float rho2 = (px - tx) * (px - tx) + (py - ty) * (py - ty);
  float ex = fmaxf(p.z, g.z) - fminf(p.x, g.x);
  float ey = fmaxf(p.w, g.w) - fminf(p.y, g.y);
  float c2 = fmaxf(ex * ex + ey * ey, EPS_);
  float pw = fmaxf(p.z - p.x, EPS_), ph = fmaxf(p.w - p.y, EPS_);
  float tw = fmaxf(g.z - g.x, EPS_), th = fmaxf(g.w - g.y, EPS_);
  float dat = atanf(tw / th) - atanf(pw / ph);
  float v = (4.0f / (float)(M_PI * M_PI)) * dat * dat;
  float alpha = v / ((1.f - iou) + v + EPS_);
  return 1.f - (iou - rho2 / c2 - alpha * v);
}

// gt_mask layout detector (int8 bool vs 4-byte elems) — unchanged (passed R1-R6)
__global__ void kdetect(const unsigned char* m8, int* flag) {
  int b = threadIdx.x;
  int ok = 1;
  const unsigned char* r = m8 + b * G_;
  if (r[0] != 1) ok = 0;
  int seen0 = 0;
  for (int g = 0; g < G_; ++g) {
    unsigned char c = r[g];
    if (c > 1) { ok = 0; break; }
    if (c == 0) seen0 = 1;
    else if (seen0) { ok = 0; break; }
  }
  int all = __all(ok);
  if (b == 0) *flag = all ? 1 : 0;
}

__device__ __forceinline__ float block_sum(float v, float* s_red) {
  for (int off = 32; off > 0; off >>= 1) v += __shfl_xor(v, off);
  int lane = threadIdx.x & 63, wid = threadIdx.x >> 6;
  if (lane == 0) s_red[wid] = v;
  __syncthreads();
  float r = 0.f;
  if (wid == 0) {
    float t = (lane < NW_) ? s_red[lane] : 0.f;
    for (int off = 32; off > 0; off >>= 1) t += __shfl_xor(t, off);
    r = t;
  }
  __syncthreads();
  return r;  // valid at tid 0
}

__device__ __forceinline__ ull wave_maxkey(ull k) {
  for (int off = 32; off > 0; off >>= 1) {
    ull o = __shfl_xor(k, off);
    if (o > k) k = o;
  }
  return k;
}

// register-resident sorted-desc top-8 insert (named regs: no scratch)
#define TOP8_INS(key)                                   \
  if ((key) > t7) {                                     \
    t7 = (key);                                         \
    ull tmp_;                                           \
    if (t7 > t6) { tmp_ = t6; t6 = t7; t7 = tmp_; }     \
    if (t6 > t5) { tmp_ = t5; t5 = t6; t6 = tmp_; }     \
    if (t5 > t4) { tmp_ = t4; t4 = t5; t5 = tmp_; }     \
    if (t4 > t3) { tmp_ = t3; t3 = t4; t4 = tmp_; }     \
    if (t3 > t2) { tmp_ = t2; t2 = t3; t3 = tmp_; }     \
    if (t2 > t1) { tmp_ = t1; t1 = t2; t2 = tmp_; }     \
    if (t1 > t0) { tmp_ = t0; t0 = t1; t1 = tmp_; }     \
  }

// register-resident sorted-desc top-16 insert
#define TOP16_INS(key)                                    \
  if ((key) > t15) {                                      \
    t15 = (key);                                          \
    ull tmp_;                                             \
    if (t15 > t14) { tmp_ = t14; t14 = t15; t15 = tmp_; } \
    if (t14 > t13) { tmp_ = t13; t13 = t14; t14 = tmp_; } \
    if (t13 > t12) { tmp_ = t12; t12 = t13; t13 = tmp_; } \
    if (t12 > t11) { tmp_ = t11; t11 = t12; t12 = tmp_; } \
    if (t11 > t10) { tmp_ = t10; t10 = t11; t11 = tmp_; } \
    if (t10 > t9)  { tmp_ = t9;  t9 = t10;  t10 = tmp_; } \
    if (t9 > t8)   { tmp_ = t8;  t8 = t9;   t9 = tmp_; }  \
    if (t8 > t7)   { tmp_ = t7;  t7 = t8;   t8 = tmp_; }  \
    if (t7 > t6)   { tmp_ = t6;  t6 = t7;   t7 = tmp_; }  \
    if (t6 > t5)   { tmp_ = t5;  t5 = t6;   t6 = tmp_; }  \
    if (t5 > t4)   { tmp_ = t4;  t4 = t5;   t5 = tmp_; }  \
    if (t4 > t3)   { tmp_ = t3;  t3 = t4;   t4 = tmp_; }  \
    if (t3 > t2)   { tmp_ = t2;  t2 = t3;   t3 = tmp_; }  \
    if (t2 > t1)   { tmp_ = t1;  t1 = t2;   t2 = tmp_; }  \
    if (t1 > t0)   { tmp_ = t0;  t0 = t1;   t1 = tmp_; }  \
  }

// ---- phase 1: exact per-column top-16 lists straight to ws ----
// grid: B*4 blocks; block = (batch, quarter of 50 cols); 20 threads/col x 200 rows
__global__ __launch_bounds__(1024) void kinit(const float* __restrict__ pred_boxes,
                                              const float* __restrict__ gt_boxes,
                                              const void* __restrict__ gt_mask,
                                              char* __restrict__ ws) {
  __shared__ float s_gx[G_], s_gy[G_], s_gz[G_], s_gw[G_], s_garea[G_];
  __shared__ unsigned char s_valid[G_];
  __shared__ ull s_mbuf[16][20][16];  // 40 KB staging (16 cols/round)
  __shared__ ull s_mint[16][4][16];   // 8 KB level-A intermediates
  const int b = blockIdx.x >> 2, q = blockIdx.x & 3;
  const int tid = threadIdx.x;
  const int msk8 = *(const int*)(ws + WS_FLAG);
  const float4* p4 = (const float4*)pred_boxes + (size_t)b * K_;
  const float4* g4 = (const float4*)gt_boxes + (size_t)b * G_;

  for (int g = tid; g < G_; g += 1024) {
    float4 gb = g4[g];
    s_gx[g] = gb.x; s_gy[g] = gb.y; s_gz[g] = gb.z; s_gw[g] = gb.w;
    s_garea[g] = box_area(gb);
    int v;
    if (msk8) v = ((const unsigned char*)gt_mask)[(size_t)b * G_ + g] != 0;
    else      v = ((const int*)gt_mask)[(size_t)b * G_ + g] != 0;
    s_valid[g] = (unsigned char)v;
  }
  __syncthreads();

  const int cl = tid / 20, j = tid - 20 * cl;  // cl<52; j in [0,20)
  const int gcol = q * 50 + cl;
  const bool active = (tid < 1000) && s_valid[gcol];
  ull t0 = 0, t1 = 0, t2 = 0, t3 = 0, t4 = 0, t5 = 0, t6 = 0, t7 = 0;
  ull t8 = 0, t9 = 0, t10 = 0, t11 = 0, t12 = 0, t13 = 0, t14 = 0, t15 = 0;
  if (active) {
    float4 gb = make_float4(s_gx[gcol], s_gy[gcol], s_gz[gcol], s_gw[gcol]);
    float gA = s_garea[gcol];
    const int k0 = j * 200;
    for (int i = 0; i < 200; ++i) {
      int k = k0 + i;
      float4 pb = p4[k];
      float iou = iou_ab(pb, box_area(pb), gb, gA);
      ull e = ((ull)__float_as_uint(iou) << 12) | (ull)(4095 - k);
      TOP16_INS(e);
    }
  }
  ull* wtop = (ull*)(ws + WS_TOP);
  for (int r = 0; r < 4; ++r) {  // 16 local cols per round (covers 50)
    int rc = cl - 16 * r;
    if (active && rc >= 0 && rc < 16) {
      s_mbuf[rc][j][0] = t0;   s_mbuf[rc][j][1] = t1;
      s_mbuf[rc][j][2] = t2;   s_mbuf[rc][j][3] = t3;
      s_mbuf[rc][j][4] = t4;   s_mbuf[rc][j][5] = t5;
      s_mbuf[rc][j][6] = t6;   s_mbuf[rc][j][7] = t7;
      s_mbuf[rc][j][8] = t8;   s_mbuf[rc][j][9] = t9;
      s_mbuf[rc][j][10] = t10; s_mbuf[rc][j][11] = t11;
      s_mbuf[rc][j][12] = t12; s_mbuf[rc][j][13] = t13;
      s_mbuf[rc][j][14] = t14; s_mbuf[rc][j][15] = t15;
    }
    __syncthreads();
    // level A: 4 threads/col each 5-way-select 16 from 5 sorted lists
    if (tid < 64) {
      int rc2 = tid >> 2, sub = tid & 3;
      int cc = 16 * r + rc2;
      if (cc < 50 && s_valid[q * 50 + cc]) {
        int base = sub * 5;
        int i0 = 0, i1 = 0, i2 = 0, i3 = 0, i4 = 0;
        for (int o = 0; o < 16; ++o) {
          ull v0 = (i0 < 16) ? s_mbuf[rc2][base + 0][i0] : 0ull;
          ull v1 = (i1 < 16) ? s_mbuf[rc2][base + 1][i1] : 0ull;
          ull v2 = (i2 < 16) ? s_mbuf[rc2][base + 2][i2] : 0ull;
          ull v3 = (i3 < 16) ? s_mbuf[rc2][base + 3][i3] : 0ull;
          ull v4 = (i4 < 16) ? s_mbuf[rc2][base + 4][i4] : 0ull;
          ull best = v0; int jb = 0;
          if (v1 > best) { best = v1; jb = 1; }
          if (v2 > best) { best = v2; jb = 2; }
          if (v3 > best) { best = v3; jb = 3; }
          if (v4 > best) { best = v4; jb = 4; }
          if (jb == 0) ++i0; else if (jb == 1) ++i1; else if (jb == 2) ++i2;
          else if (jb == 3) ++i3; else ++i4;
          s_mint[rc2][sub][o] = best;
        }
      }
    }
    __syncthreads();
    // level B: 1 thread/col 4-way-select 16 -> final exact top-16 -> ws
    if (tid < 16) {
      int cc = 16 * r + tid;
      if (cc < 50) {
        int gc = q * 50 + cc;
        ull* dst = wtop + ((size_t)b * G_ + gc) * 16;
        if (s_valid[gc]) {
          int i0 = 0, i1 = 0, i2 = 0, i3 = 0;
          for (int o = 0; o < 16; ++o) {
            ull v0 = (i0 < 16) ? s_mint[tid][0][i0] : 0ull;
            ull v1 = (i1 < 16) ? s_mint[tid][1][i1] : 0ull;
            ull v2 = (i2 < 16) ? s_mint[tid][2][i2] : 0ull;
            ull v3 = (i3 < 16) ? s_mint[tid][3][i3] : 0ull;
            ull best = v0; int jb = 0;
            if (v1 > best) { best = v1; jb = 1; }
            if (v2 > best) { best = v2; jb = 2; }
            if (v3 > best) { best = v3; jb = 3; }
            if (jb == 0) ++i0; else if (jb == 1) ++i1; else if (jb == 2) ++i2;
            else ++i3;
            dst[o] = best;
          }
        } else {
          for (int o = 0; o < 16; ++o) dst[o] = 0ull;
        }
      }
    }
    __syncthreads();
  }
}

// ---- phase 2: greedy matching, 1 wave/batch, zero barriers, double-pop ----
__global__ __launch_bounds__(64) void kmatch(const float* __restrict__ pred_boxes,
                                             const float* __restrict__ gt_boxes,
                                             char* __restrict__ ws) {
  __shared__ float s_gx[G_], s_gy[G_], s_gz[G_], s_gw[G_], s_garea[G_];
  __shared__ unsigned char s_rowused[4096];  // padded: speculative reads safe
  __shared__ ull s_toplist[G_][17];          // stride 17: bank-spread walks
  __shared__ int s_mp[G_];
  __shared__ unsigned short s_mg[G_];
  const int b = blockIdx.x;
  const int lane = threadIdx.x;
  const float4* p4 = (const float4*)pred_boxes + (size_t)b * K_;
  const float4* g4 = (const float4*)gt_boxes + (size_t)b * G_;

  for (int g = lane; g < G_; g += 64) {
    float4 gb = g4[g];
    s_gx[g] = gb.x; s_gy[g] = gb.y; s_gz[g] = gb.z; s_gw[g] = gb.w;
    s_garea[g] = box_area(gb);
  }
  for (int k = lane; k < 4096; k += 64) s_rowused[k] = 0;

  const ull* wtop = (const ull*)(ws + WS_TOP);
  ull key0 = 0, key1 = 0, key2 = 0, key3 = 0;
  int ptr0 = 16, ptr1 = 16, ptr2 = 16, ptr3 = 16;
  int cloc = 0;
#define SLOTLOAD(S)                                                         \
  { int col = S * 64 + lane;                                                \
    if (col < G_) {                                                         \
      const ull* src_ = wtop + ((size_t)b * G_ + col) * 16;                 \
      ull h_ = src_[0];                                                     \
      s_toplist[col][0] = h_;                                               \
      _Pragma("unroll") for (int o = 1; o < 16; ++o)                        \
        s_toplist[col][o] = src_[o];                                        \
      if (h_ != 0ull) {                                                     \
        key##S = (h_ << 8) | (ull)(255 - col); ptr##S = 1; ++cloc; } } }
  SLOTLOAD(0) SLOTLOAD(1) SLOTLOAD(2) SLOTLOAD(3)
#undef SLOTLOAD
  for (int off = 32; off > 0; off >>= 1) cloc += __shfl_xor(cloc, off);
  const int cnt = cloc;
  __builtin_amdgcn_wave_barrier();

  for (int step = 0; step < cnt;) {
    // lane-local top-2 of 4 slots
    ull a1 = key0, a2 = key1;
    if (key1 > key0) { a1 = key1; a2 = key0; }
    if (key2 > a1) { a2 = a1; a1 = key2; } else if (key2 > a2) a2 = key2;
    if (key3 > a1) { a2 = a1; a1 = key3; } else if (key3 > a2) a2 = key3;
    // wave top-2 reduce
    for (int off = 32; off > 0; off >>= 1) {
      ull b1 = __shfl_xor(a1, off), b2 = __shfl_xor(a2, off);
      if (b1 > a1) { a2 = (a1 > b2) ? a1 : b2; a1 = b1; }
      else { a2 = (b1 > a2) ? b1 : a2; }
    }
    const int p1 = 4095 - (int)((a1 >> 8) & 0xFFF);
    const int g1v = 255 - (int)(a1 & 0xFF);
    const int p2 = 4095 - (int)((a2 >> 8) & 0xFFF);
    const int g2v = 255 - (int)(a2 & 0xFF);
    // #1 and #2 are always different cols; if rows differ too, #2 is exactly
    // the next greedy pick (pop-1 demotions only touch cols whose row == p1).
    const bool do2 = (a2 != 0ull) && (p2 != p1) && (step + 1 < cnt);
    if (lane == 0) {
      s_mp[step] = p1; s_mg[step] = (unsigned short)g1v; s_rowused[p1] = 1;
      if (do2) { s_mp[step + 1] = p2; s_mg[step + 1] = (unsigned short)g2v; s_rowused[p2] = 1; }
    }
    __builtin_amdgcn_wave_barrier();
    const int gd2 = do2 ? g2v : -1;
    const int pd2 = do2 ? p2 : -1;
    int need = 0;
#define DEMOTE(S)                                                           \
    { int col = S * 64 + lane; ull kk = key##S;                             \
      if (kk != 0ull) {                                                     \
        if (col == g1v || col == gd2) { key##S = 0ull; }                    \
        else { int krow = 4095 - (int)((kk >> 8) & 0xFFF);                  \
          if (krow == p1 || krow == pd2) {                                  \
            ull nk = 0ull; int np = ptr##S;                                 \
            while (np < 16) {                                               \
              ull e = s_toplist[col][np]; ++np;                             \
              if (e == 0ull) { np = 16; break; }                            \
              int pr = 4095 - (int)((e >> 12) & 0xFFF);                     \
              if (!s_rowused[pr]) { nk = (e << 8) | (ull)(255 - col); break; } \
            }                                                               \
            ptr##S = np; key##S = nk;                                       \
            if (nk == 0ull) need |= (1 << S); } } } }
    DEMOTE(0) DEMOTE(1) DEMOTE(2) DEMOTE(3)
#undef DEMOTE
    // exact fallback: full rescan, refilling an exact top-8 over unused rows
    while (__any(need)) {
      unsigned long long bal = __ballot(need != 0);
      int src = (int)__builtin_ctzll(bal);
      int myslot = need ? __builtin_ctz(need) : 0;
      int slot = __shfl(myslot, src);
      int col = slot * 64 + src;
      float4 gb = make_float4(s_gx[col], s_gy[col], s_gz[col], s_gw[col]);
      float gA = s_garea[col];
      ull t0 = 0, t1 = 0, t2 = 0, t3 = 0, t4 = 0, t5 = 0, t6 = 0, t7 = 0;
#pragma unroll 2
      for (int k = lane; k < K_; k += 64) {
        if (!s_rowused[k]) {
          float4 pb = p4[k];
          float iou = iou_ab(pb, box_area(pb), gb, gA);
          ull e = ((ull)__float_as_uint(iou) << 12) | (ull)(4095 - k);
          TOP8_INS(e);
        }
      }
      ull newhead = 0ull;
#pragma unroll
      for (int o = 0; o < 8; ++o) {
        ull m = wave_maxkey(t0);
        if (o == 0) newhead = m;
        if (t0 == m && m != 0ull) {
          t0 = t1; t1 = t2; t2 = t3; t3 = t4; t4 = t5; t5 = t6; t6 = t7; t7 = 0;
        }
        if (lane == src) s_toplist[col][o] = m;
      }
      if (lane == src) {
        for (int o = 8; o < 16; ++o) s_toplist[col][o] = 0ull;
        ull nk = newhead ? ((newhead << 8) | (ull)(255 - col)) : 0ull;
        if (slot == 0) { key0 = nk; ptr0 = 1; }
        else if (slot == 1) { key1 = nk; ptr1 = 1; }
        else if (slot == 2) { key2 = nk; ptr2 = 1; }
        else { key3 = nk; ptr3 = 1; }
        need &= ~(1 << slot);
      }
      __builtin_amdgcn_wave_barrier();
    }
    step += do2 ? 2 : 1;
  }

  // dump results for kepi
  unsigned* mout = (unsigned*)(ws + WS_MATCH) + b * G_;
  for (int i = lane; i < cnt; i += 64)
    mout[i] = ((unsigned)s_mp[i] << 8) | (unsigned)s_mg[i];
  unsigned* ruo = (unsigned*)(ws + WS_ROWUSED + (size_t)b * K_);
  const unsigned* rus = (const unsigned*)s_rowused;
  for (int i = lane; i < K_ / 4; i += 64) ruo[i] = rus[i];
  if (lane == 0) ((int*)(ws + WS_CNT))[b] = cnt;
}

// ---- phase 3: CIoU + CE over matches, BCE objectness over all K ----
__global__ __launch_bounds__(1024) void kepi(const float* __restrict__ pred_boxes,
                                             const float* __restrict__ obj_logits,
                                             const float* __restrict__ cls_logits,
                                             const float* __restrict__ gt_boxes,
                                             const int* __restrict__ gt_labels,
                                             char* __restrict__ ws) {
  __shared__ float s_red[NW_];
  const int b = blockIdx.x;
  const int tid = threadIdx.x;
  const int cnt = ((const int*)(ws + WS_CNT))[b];
  const unsigned* mm = (const unsigned*)(ws + WS_MATCH) + b * G_;
  const unsigned char* ru = (const unsigned char*)(ws + WS_ROWUSED) + (size_t)b * K_;
  const float4* p4 = (const float4*)pred_boxes + (size_t)b * K_;
  const float4* g4 = (const float4*)gt_boxes + (size_t)b * G_;

  float lbox = 0.f, lcls = 0.f;
  for (int i = tid; i < cnt; i += 1024) {
    unsigned e = mm[i];
    int p = (int)(e >> 8), g = (int)(e & 0xFF);
    float4 pb = p4[p];
    float4 gb = g4[g];
    lbox += ciou_loss(pb, gb);
    int label = gt_labels[(size_t)b * G_ + g];
    const float* lg = cls_logits + ((size_t)b * K_ + p) * C_;
    float m = -1e30f;
    for (int cc = 0; cc < C_; ++cc) m = fmaxf(m, lg[cc]);
    float s = 0.f;
    for (int cc = 0; cc < C_; ++cc) s += expf(lg[cc] - m);
    lcls += (m + logf(s)) - lg[label];
  }
  float obj = 0.f;
  const float* ol = obj_logits + (size_t)b * K_;
  for (int k = tid; k < K_; k += 1024) {
    float x = ol[k];
    float sp = fmaxf(x, 0.f) + log1pf(expf(-fabsf(x)));  // softplus(x)
    if (ru[k]) sp -= x;                                  // - t*x
    obj += sp;
  }
  lbox = block_sum(lbox, s_red);
  lcls = block_sum(lcls, s_red);
  obj = block_sum(obj, s_red);
  if (tid == 0) {
    float* partials = (float*)(ws + WS_PART);
    float n = (float)cnt;
    float denom = fmaxf(n, 1.f);
    partials[b * 4 + 0] = lbox / denom;
    partials[b * 4 + 1] = lcls / denom;
    partials[b * 4 + 2] = obj;
    partials[b * 4 + 3] = (n > 0.f) ? 1.f : 0.f;
  }
}

__global__ void kfinal(const char* __restrict__ ws, float* __restrict__ out) {
  int b = threadIdx.x;  // 64 threads, one wave
  const float* partials = (const float*)(ws + WS_PART);
  float lb = partials[b * 4 + 0], lc = partials[b * 4 + 1];
  float ob = partials[b * 4 + 2], hf = partials[b * 4 + 3];
  float sb = lb * hf, sc = lc * hf, sh = hf, so = ob;
  for (int off = 32; off > 0; off >>= 1) {
    sb += __shfl_xor(sb, off);
    sc += __shfl_xor(sc, off);
    sh += __shfl_xor(sh, off);
    so += __shfl_xor(so, off);
  }
  if (b == 0) {
    float nb = fmaxf(sh, 1.f);
    float box = sb / nb, cls = sc / nb;
    float obj = so / (float)(B_ * K_);
    out[0] = 5.f * box + cls + obj;
    out[1] = box;
    out[2] = cls;
    out[3] = obj;
  }
}

extern "C" void kernel_launch(void* const* d_in, const int* in_sizes, int n_in,
                              void* d_out, int out_size, void* d_ws, size_t ws_size,
                              hipStream_t stream) {
  const float* pred_boxes = (const float*)d_in[0];
  const float* obj_logits = (const float*)d_in[1];
  const float* cls_logits = (const float*)d_in[2];
  const float* gt_boxes = (const float*)d_in[3];
  const int* gt_labels = (const int*)d_in[4];
  const void* gt_mask = d_in[5];
  float* out = (float*)d_out;
  char* ws = (char*)d_ws;

  hipLaunchKernelGGL(kdetect, dim3(1), dim3(64), 0, stream,
                     (const unsigned char*)gt_mask, (int*)(ws + WS_FLAG));
  hipLaunchKernelGGL(kinit, dim3(B_ * 4), dim3(1024), 0, stream,
                     pred_boxes, gt_boxes, gt_mask, ws);
  hipLaunchKernelGGL(kmatch, dim3(B_), dim3(64), 0, stream,
                     pred_boxes, gt_boxes, ws);
  hipLaunchKernelGGL(kepi, dim3(B_), dim3(1024), 0, stream,
                     pred_boxes, obj_logits, cls_logits, gt_boxes, gt_labels, ws);
  hipLaunchKernelGGL(kfinal, dim3(1), dim3(64), 0, stream, ws, out);
}

// Round 8
// 295.654 us; speedup vs baseline: 2.3136x; 1.2760x over previous
//
#include <hip/hip_runtime.h>
#include <math.h>

#define B_ 64
#define K_ 4000
#define G_ 200
#define C_ 91
#define EPS_ 1e-9f
#define NW_ 16
#define DEPTH_ 24
typedef unsigned long long ull;

// ws layout (byte offsets); total use ~2.8 MB
#define WS_FLAG 0
#define WS_PART 256        // 64*4 f32
#define WS_CNT 1536        // 64 int
#define WS_MATCH 2048      // 64*200 u32 (p<<8|g)
#define WS_ROWUSED 53248   // 64*4000 bytes
#define WS_TOP 327680      // 64*200*24 ull = 2.46 MB (exact top-L lists, L<=24)

// list key: (iou_bits << 12) | (4095 - p)   — iou desc, then p asc; always > 0
// full key: (list << 8) | (255 - g)         — iou desc, p asc, g asc == argmax flat order
__device__ __forceinline__ float box_area(float4 a) {
#pragma clang fp contract(off)
  return fmaxf(a.z - a.x, 0.f) * fmaxf(a.w - a.y, 0.f);
}

// IoU; contract(off) => bit-identical across init and rescan
__device__ __forceinline__ float iou_ab(float4 a, float aA, float4 b, float aB) {
#pragma clang fp contract(off)
  float tlx = fmaxf(a.x, b.x), tly = fmaxf(a.y, b.y);
  float brx = fminf(a.z, b.z), bry = fminf(a.w, b.w);
  float w = fmaxf(brx - tlx, 0.f), h = fmaxf(bry - tly, 0.f);
  float inter = w * h;
  float uni = fmaxf(aA + aB - inter, EPS_);
  return inter / uni;
}

__device__ __forceinline__ float ciou_loss(float4 p, float4 g) {
  float tlx = fmaxf(p.x, g.x), tly = fmaxf(p.y, g.y);
  float brx = fminf(p.z, g.z), bry = fminf(p.w, g.w);
  float w = fmaxf(brx - tlx, 0.f), h = fmaxf(bry - tly, 0.f);
  float inter = w * h;
  float areaP = fmaxf(p.z - p.x, 0.f) * fmaxf(p.w - p.y, 0.f);
  float areaG = fmaxf(g.z - g.x, 0.f) * fmaxf(g.w - g.y, 0.f);
  float iou = inter / fmaxf(areaP + areaG - inter, EPS_);
  float px = (p.x + p.z) * 0.5f, py = (p.y + p.w) * 0.5f;
  float tx = (g.x + g.z) * 0.5f, ty = (g.y + g.w) * 0.5f;
  float rho2 = (px - tx) * (px - tx) + (py - ty) * (py - ty);
  float ex = fmaxf(p.z, g.z) - fminf(p.x, g.x);
  float ey = fmaxf(p.w, g.w) - fminf(p.y, g.y);
  float c2 = fmaxf(ex * ex + ey * ey, EPS_);
  float pw = fmaxf(p.z - p.x, EPS_), ph = fmaxf(p.w - p.y, EPS_);
  float tw = fmaxf(g.z - g.x, EPS_), th = fmaxf(g.w - g.y, EPS_);
  float dat = atanf(tw / th) - atanf(pw / ph);
  float v = (4.0f / (float)(M_PI * M_PI)) * dat * dat;
  float alpha = v / ((1.f - iou) + v + EPS_);
  return 1.f - (iou - rho2 / c2 - alpha * v);
}

// gt_mask layout detector (int8 bool vs 4-byte elems) — unchanged (passed R1-R7)
__global__ void kdetect(const unsigned char* m8, int* flag) {
  int b = threadIdx.x;
  int ok = 1;
  const unsigned char* r = m8 + b * G_;
  if (r[0] != 1) ok = 0;
  int seen0 = 0;
  for (int g = 0; g < G_; ++g) {
    unsigned char c = r[g];
    if (c > 1) { ok = 0; break; }
    if (c == 0) seen0 = 1;
    else if (seen0) { ok = 0; break; }
  }
  int all = __all(ok);
  if (b == 0) *flag = all ? 1 : 0;
}

__device__ __forceinline__ float block_sum(float v, float* s_red) {
  for (int off = 32; off > 0; off >>= 1) v += __shfl_xor(v, off);
  int lane = threadIdx.x & 63, wid = threadIdx.x >> 6;
  if (lane == 0) s_red[wid] = v;
  __syncthreads();
  float r = 0.f;
  if (wid == 0) {
    float t = (lane < NW_) ? s_red[lane] : 0.f;
    for (int off = 32; off > 0; off >>= 1) t += __shfl_xor(t, off);
    r = t;
  }
  __syncthreads();
  return r;  // valid at tid 0
}

__device__ __forceinline__ ull wave_maxkey(ull k) {
  for (int off = 32; off > 0; off >>= 1) {
    ull o = __shfl_xor(k, off);
    if (o > k) k = o;
  }
  return k;
}

// register-resident sorted-desc top-8 insert (named regs: no scratch)
#define TOP8_INS(key)                                   \
  if ((key) > t7) {                                     \
    t7 = (key);                                         \
    ull tmp_;                                           \
    if (t7 > t6) { tmp_ = t6; t6 = t7; t7 = tmp_; }     \
    if (t6 > t5) { tmp_ = t5; t5 = t6; t6 = tmp_; }     \
    if (t5 > t4) { tmp_ = t4; t4 = t5; t5 = tmp_; }     \
    if (t4 > t3) { tmp_ = t3; t3 = t4; t4 = tmp_; }     \
    if (t3 > t2) { tmp_ = t2; t2 = t3; t3 = tmp_; }     \
    if (t2 > t1) { tmp_ = t1; t1 = t2; t2 = tmp_; }     \
    if (t1 > t0) { tmp_ = t0; t0 = t1; t1 = tmp_; }     \
  }

// ---- phase 1: wave-per-column exact top-L lists (L<=24, drain-stop) ----
// grid: B*8 blocks; block = (batch, octant of 25 cols); wave w handles cols w, w+16
__global__ __launch_bounds__(1024) void kinit(const float* __restrict__ pred_boxes,
                                              const float* __restrict__ gt_boxes,
                                              const void* __restrict__ gt_mask,
                                              char* __restrict__ ws) {
  __shared__ float4 s_p[K_];  // 64 KB staged pred boxes
  const int blk = blockIdx.x;
  const int b = blk >> 3, oct = blk & 7;
  const int tid = threadIdx.x, lane = tid & 63, wid = tid >> 6;
  const int msk8 = *(const int*)(ws + WS_FLAG);
  const float4* p4 = (const float4*)pred_boxes + (size_t)b * K_;
  const float4* g4 = (const float4*)gt_boxes + (size_t)b * G_;

  for (int i = tid; i < K_; i += 1024) s_p[i] = p4[i];
  __syncthreads();

  ull* wtop = (ull*)(ws + WS_TOP);
  for (int cc = wid; cc < 25; cc += 16) {
    const int col = oct * 25 + cc;
    ull* dst = wtop + ((size_t)b * G_ + col) * DEPTH_;
    int v;
    if (msk8) v = ((const unsigned char*)gt_mask)[(size_t)b * G_ + col] != 0;
    else      v = ((const int*)gt_mask)[(size_t)b * G_ + col] != 0;
    if (!v) {
      for (int o = lane; o < DEPTH_; o += 64) dst[o] = 0ull;
      continue;
    }
    float4 gb = g4[col];
    float gA = box_area(gb);
    ull t0 = 0, t1 = 0, t2 = 0, t3 = 0, t4 = 0, t5 = 0, t6 = 0, t7 = 0;
    for (int k = lane; k < K_; k += 64) {
      float4 pb = s_p[k];
      float iou = iou_ab(pb, box_area(pb), gb, gA);
      ull e = ((ull)__float_as_uint(iou) << 12) | (ull)(4095 - k);
      TOP8_INS(e);
    }
    // drain-stop extraction: entries written are the exact global top-`written`
    int supplied = 0, written = 0;
    for (int o = 0; o < DEPTH_; ++o) {
      ull m = wave_maxkey(t0);
      if (m == 0ull) break;
      int dn = 0;
      if (t0 == m) {  // unique keys -> exactly one lane
        t0 = t1; t1 = t2; t2 = t3; t3 = t4; t4 = t5; t5 = t6; t6 = t7; t7 = 0;
        if (++supplied == 8) dn = 1;  // lane emptied: beyond here unsafe
      }
      if (lane == 0) dst[o] = m;
      ++written;
      if (__any(dn)) break;
    }
    for (int o = written + lane; o < DEPTH_; o += 64) dst[o] = 0ull;
  }
}

// ---- phase 2: greedy matching, 1 wave/batch, zero barriers, double-pop ----
__global__ __launch_bounds__(64) void kmatch(const float* __restrict__ pred_boxes,
                                             const float* __restrict__ gt_boxes,
                                             char* __restrict__ ws) {
  __shared__ float s_gx[G_], s_gy[G_], s_gz[G_], s_gw[G_], s_garea[G_];
  __shared__ unsigned char s_rowused[4096];   // padded: speculative reads safe
  __shared__ ull s_toplist[G_][DEPTH_ + 1];   // stride 25: bank-spread walks
  __shared__ int s_mp[G_];
  __shared__ unsigned short s_mg[G_];
  const int b = blockIdx.x;
  const int lane = threadIdx.x;
  const float4* p4 = (const float4*)pred_boxes + (size_t)b * K_;
  const float4* g4 = (const float4*)gt_boxes + (size_t)b * G_;

  for (int g = lane; g < G_; g += 64) {
    float4 gb = g4[g];
    s_gx[g] = gb.x; s_gy[g] = gb.y; s_gz[g] = gb.z; s_gw[g] = gb.w;
    s_garea[g] = box_area(gb);
  }
  for (int k = lane; k < 4096; k += 64) s_rowused[k] = 0;

  const ull* wtop = (const ull*)(ws + WS_TOP);
  ull key0 = 0, key1 = 0, key2 = 0, key3 = 0;
  int ptr0 = DEPTH_, ptr1 = DEPTH_, ptr2 = DEPTH_, ptr3 = DEPTH_;
  int cloc = 0;
#define SLOTLOAD(S)                                                         \
  { int col = S * 64 + lane;                                                \
    if (col < G_) {                                                         \
      const ull* src_ = wtop + ((size_t)b * G_ + col) * DEPTH_;             \
      ull h_ = src_[0];                                                     \
      s_toplist[col][0] = h_;                                               \
      _Pragma("unroll") for (int o = 1; o < DEPTH_; ++o)                    \
        s_toplist[col][o] = src_[o];                                        \
      if (h_ != 0ull) {                                                     \
        key##S = (h_ << 8) | (ull)(255 - col); ptr##S = 1; ++cloc; } } }
  SLOTLOAD(0) SLOTLOAD(1) SLOTLOAD(2) SLOTLOAD(3)
#undef SLOTLOAD
  for (int off = 32; off > 0; off >>= 1) cloc += __shfl_xor(cloc, off);
  const int cnt = cloc;
  __builtin_amdgcn_wave_barrier();

  for (int step = 0; step < cnt;) {
    // lane-local top-2 of 4 slots
    ull a1 = key0, a2 = key1;
    if (key1 > key0) { a1 = key1; a2 = key0; }
    if (key2 > a1) { a2 = a1; a1 = key2; } else if (key2 > a2) a2 = key2;
    if (key3 > a1) { a2 = a1; a1 = key3; } else if (key3 > a2) a2 = key3;
    // wave top-2 reduce
    for (int off = 32; off > 0; off >>= 1) {
      ull b1 = __shfl_xor(a1, off), b2 = __shfl_xor(a2, off);
      if (b1 > a1) { a2 = (a1 > b2) ? a1 : b2; a1 = b1; }
      else { a2 = (b1 > a2) ? b1 : a2; }
    }
    const int p1 = 4095 - (int)((a1 >> 8) & 0xFFF);
    const int g1v = 255 - (int)(a1 & 0xFF);
    const int p2 = 4095 - (int)((a2 >> 8) & 0xFFF);
    const int g2v = 255 - (int)(a2 & 0xFF);
    // #1 and #2 are always different cols; if rows differ too, #2 is exactly
    // the next greedy pick (pop-1 demotions only touch cols whose row == p1).
    const bool do2 = (a2 != 0ull) && (p2 != p1) && (step + 1 < cnt);
    if (lane == 0) {
      s_mp[step] = p1; s_mg[step] = (unsigned short)g1v; s_rowused[p1] = 1;
      if (do2) { s_mp[step + 1] = p2; s_mg[step + 1] = (unsigned short)g2v; s_rowused[p2] = 1; }
    }
    __builtin_amdgcn_wave_barrier();
    const int gd2 = do2 ? g2v : -1;
    const int pd2 = do2 ? p2 : -1;
    int need = 0;
#define DEMOTE(S)                                                           \
    { int col = S * 64 + lane; ull kk = key##S;                             \
      if (kk != 0ull) {                                                     \
        if (col == g1v || col == gd2) { key##S = 0ull; }                    \
        else { int krow = 4095 - (int)((kk >> 8) & 0xFFF);                  \
          if (krow == p1 || krow == pd2) {                                  \
            ull nk = 0ull; int np = ptr##S;                                 \
            while (np < DEPTH_) {                                           \
              ull e = s_toplist[col][np]; ++np;                             \
              if (e == 0ull) { np = DEPTH_; break; }                        \
              int pr = 4095 - (int)((e >> 12) & 0xFFF);                     \
              if (!s_rowused[pr]) { nk = (e << 8) | (ull)(255 - col); break; } \
            }                                                               \
            ptr##S = np; key##S = nk;                                       \
            if (nk == 0ull) need |= (1 << S); } } } }
    DEMOTE(0) DEMOTE(1) DEMOTE(2) DEMOTE(3)
#undef DEMOTE
    // exact fallback: full rescan, drain-stop refill of up to DEPTH_ entries
    while (__any(need)) {
      unsigned long long bal = __ballot(need != 0);
      int src = (int)__builtin_ctzll(bal);
      int myslot = need ? __builtin_ctz(need) : 0;
      int slot = __shfl(myslot, src);
      int col = slot * 64 + src;
      float4 gb = make_float4(s_gx[col], s_gy[col], s_gz[col], s_gw[col]);
      float gA = s_garea[col];
      ull t0 = 0, t1 = 0, t2 = 0, t3 = 0, t4 = 0, t5 = 0, t6 = 0, t7 = 0;
#pragma unroll 2
      for (int k = lane; k < K_; k += 64) {
        if (!s_rowused[k]) {
          float4 pb = p4[k];
          float iou = iou_ab(pb, box_area(pb), gb, gA);
          ull e = ((ull)__float_as_uint(iou) << 12) | (ull)(4095 - k);
          TOP8_INS(e);
        }
      }
      ull newhead = 0ull;
      int supplied = 0, written = 0;
      for (int o = 0; o < DEPTH_; ++o) {
        ull m = wave_maxkey(t0);
        if (m == 0ull) break;
        if (o == 0) newhead = m;
        int dn = 0;
        if (t0 == m) {
          t0 = t1; t1 = t2; t2 = t3; t3 = t4; t4 = t5; t5 = t6; t6 = t7; t7 = 0;
          if (++supplied == 8) dn = 1;
        }
        if (lane == src) s_toplist[col][o] = m;
        ++written;
        if (__any(dn)) break;
      }
      if (lane == src) {
        for (int o = written; o < DEPTH_; ++o) s_toplist[col][o] = 0ull;
        ull nk = newhead ? ((newhead << 8) | (ull)(255 - col)) : 0ull;
        if (slot == 0) { key0 = nk; ptr0 = 1; }
        else if (slot == 1) { key1 = nk; ptr1 = 1; }
        else if (slot == 2) { key2 = nk; ptr2 = 1; }
        else { key3 = nk; ptr3 = 1; }
        need &= ~(1 << slot);
      }
      __builtin_amdgcn_wave_barrier();
    }
    step += do2 ? 2 : 1;
  }

  // dump results for kepi
  unsigned* mout = (unsigned*)(ws + WS_MATCH) + b * G_;
  for (int i = lane; i < cnt; i += 64)
    mout[i] = ((unsigned)s_mp[i] << 8) | (unsigned)s_mg[i];
  unsigned* ruo = (unsigned*)(ws + WS_ROWUSED + (size_t)b * K_);
  const unsigned* rus = (const unsigned*)s_rowused;
  for (int i = lane; i < K_ / 4; i += 64) ruo[i] = rus[i];
  if (lane == 0) ((int*)(ws + WS_CNT))[b] = cnt;
}

// ---- phase 3: CIoU + CE over matches, BCE objectness over all K ----
__global__ __launch_bounds__(1024) void kepi(const float* __restrict__ pred_boxes,
                                             const float* __restrict__ obj_logits,
                                             const float* __restrict__ cls_logits,
                                             const float* __restrict__ gt_boxes,
                                             const int* __restrict__ gt_labels,
                                             char* __restrict__ ws) {
  __shared__ float s_red[NW_];
  const int b = blockIdx.x;
  const int tid = threadIdx.x;
  const int cnt = ((const int*)(ws + WS_CNT))[b];
  const unsigned* mm = (const unsigned*)(ws + WS_MATCH) + b * G_;
  const unsigned char* ru = (const unsigned char*)(ws + WS_ROWUSED) + (size_t)b * K_;
  const float4* p4 = (const float4*)pred_boxes + (size_t)b * K_;
  const float4* g4 = (const float4*)gt_boxes + (size_t)b * G_;

  float lbox = 0.f, lcls = 0.f;
  for (int i = tid; i < cnt; i += 1024) {
    unsigned e = mm[i];
    int p = (int)(e >> 8), g = (int)(e & 0xFF);
    float4 pb = p4[p];
    float4 gb = g4[g];
    lbox += ciou_loss(pb, gb);
    int label = gt_labels[(size_t)b * G_ + g];
    const float* lg = cls_logits + ((size_t)b * K_ + p) * C_;
    float m = -1e30f;
    for (int cc = 0; cc < C_; ++cc) m = fmaxf(m, lg[cc]);
    float s = 0.f;
    for (int cc = 0; cc < C_; ++cc) s += expf(lg[cc] - m);
    lcls += (m + logf(s)) - lg[label];
  }
  float obj = 0.f;
  const float* ol = obj_logits + (size_t)b * K_;
  for (int k = tid; k < K_; k += 1024) {
    float x = ol[k];
    float sp = fmaxf(x, 0.f) + log1pf(expf(-fabsf(x)));  // softplus(x)
    if (ru[k]) sp -= x;                                  // - t*x
    obj += sp;
  }
  lbox = block_sum(lbox, s_red);
  lcls = block_sum(lcls, s_red);
  obj = block_sum(obj, s_red);
  if (tid == 0) {
    float* partials = (float*)(ws + WS_PART);
    float n = (float)cnt;
    float denom = fmaxf(n, 1.f);
    partials[b * 4 + 0] = lbox / denom;
    partials[b * 4 + 1] = lcls / denom;
    partials[b * 4 + 2] = obj;
    partials[b * 4 + 3] = (n > 0.f) ? 1.f : 0.f;
  }
}

__global__ void kfinal(const char* __restrict__ ws, float* __restrict__ out) {
  int b = threadIdx.x;  // 64 threads, one wave
  const float* partials = (const float*)(ws + WS_PART);
  float lb = partials[b * 4 + 0], lc = partials[b * 4 + 1];
  float ob = partials[b * 4 + 2], hf = partials[b * 4 + 3];
  float sb = lb * hf, sc = lc * hf, sh = hf, so = ob;
  for (int off = 32; off > 0; off >>= 1) {
    sb += __shfl_xor(sb, off);
    sc += __shfl_xor(sc, off);
    sh += __shfl_xor(sh, off);
    so += __shfl_xor(so, off);
  }
  if (b == 0) {
    float nb = fmaxf(sh, 1.f);
    float box = sb / nb, cls = sc / nb;
    float obj = so / (float)(B_ * K_);
    out[0] = 5.f * box + cls + obj;
    out[1] = box;
    out[2] = cls;
    out[3] = obj;
  }
}

extern "C" void kernel_launch(void* const* d_in, const int* in_sizes, int n_in,
                              void* d_out, int out_size, void* d_ws, size_t ws_size,
                              hipStream_t stream) {
  const float* pred_boxes = (const float*)d_in[0];
  const float* obj_logits = (const float*)d_in[1];
  const float* cls_logits = (const float*)d_in[2];
  const float* gt_boxes = (const float*)d_in[3];
  const int* gt_labels = (const int*)d_in[4];
  const void* gt_mask = d_in[5];
  float* out = (float*)d_out;
  char* ws = (char*)d_ws;

  hipLaunchKernelGGL(kdetect, dim3(1), dim3(64), 0, stream,
                     (const unsigned char*)gt_mask, (int*)(ws + WS_FLAG));
  hipLaunchKernelGGL(kinit, dim3(B_ * 8), dim3(1024), 0, stream,
                     pred_boxes, gt_boxes, gt_mask, ws);
  hipLaunchKernelGGL(kmatch, dim3(B_), dim3(64), 0, stream,
                     pred_boxes, gt_boxes, ws);
  hipLaunchKernelGGL(kepi, dim3(B_), dim3(1024), 0, stream,
                     pred_boxes, obj_logits, cls_logits, gt_boxes, gt_labels, ws);
  hipLaunchKernelGGL(kfinal, dim3(1), dim3(64), 0, stream, ws, out);
}